// Round 1
// 263.659 us; speedup vs baseline: 1.0583x; 1.0583x over previous
//
#include <hip/hip_runtime.h>

#define Bn 4
#define Sn 2048
#define Dn 1024
#define Hn 16
#define DHn 64

typedef float f32x4 __attribute__((ext_vector_type(4)));
typedef short bf16x8 __attribute__((ext_vector_type(8)));
typedef unsigned short u16;
typedef unsigned int u32;
typedef unsigned short u16x8 __attribute__((ext_vector_type(8)));
typedef unsigned short u16x4 __attribute__((ext_vector_type(4)));
typedef u32 u32x4 __attribute__((ext_vector_type(4)));

union B8 { u32x4 u; bf16x8 s; u16x8 h; };

__device__ __forceinline__ u16 f2bf(float f){
  union { float f; u32 u; } v; v.f = f;
  return (u16)((v.u + 0x7fffu + ((v.u >> 16) & 1u)) >> 16);
}

// truncating pack: two fp32 -> {bf16(lo) | bf16(hi)<<16}. P>0 -> -0.2% uniform bias, negligible.
__device__ __forceinline__ u32 pack_bf2(float lo, float hi){
  union { float f; u32 u; } a, b;
  a.f = lo; b.f = hi;
  return __builtin_amdgcn_perm(b.u, a.u, 0x07060302u);
}

#if __has_builtin(__builtin_amdgcn_exp2f)
#define EXP2(x) __builtin_amdgcn_exp2f(x)
#define QSCALE 0.18033688011112042f   /* 0.125 * log2(e) */
#else
#define EXP2(x) __expf(x)
#define QSCALE 0.125f
#endif

#if __has_builtin(__builtin_amdgcn_global_load_lds)
#define G2L16(l, g) __builtin_amdgcn_global_load_lds((const __attribute__((address_space(1))) u32*)(g), \
                                                     (__attribute__((address_space(3))) u32*)(l), 16, 0, 0)
#else
#define G2L16(l, g) (*(bf16x8*)(l) = *(const bf16x8*)(g))
#endif

// ---------------- merged prep: cast x (blocks 0..4095) + 4 weights (4096..5119) ----------------
__global__ void prep_kernel(const float* __restrict__ x,
                            const float* __restrict__ Wq, const float* __restrict__ Wk,
                            const float* __restrict__ Wv, const float* __restrict__ Wo,
                            u16* __restrict__ xb, u16* __restrict__ wt_all){
  __shared__ u16 tile[64*66];
  const int t = threadIdx.x;
  if (blockIdx.x < 4096){
    size_t i = ((size_t)blockIdx.x * 256 + t) * 8;
    float4 f0 = *(const float4*)(x + i);
    float4 f1 = *(const float4*)(x + i + 4);
    u16x8 o;
    o[0]=f2bf(f0.x); o[1]=f2bf(f0.y); o[2]=f2bf(f0.z); o[3]=f2bf(f0.w);
    o[4]=f2bf(f1.x); o[5]=f2bf(f1.y); o[6]=f2bf(f1.z); o[7]=f2bf(f1.w);
    *(u16x8*)(xb + i) = o;
    return;
  }
  const int wi = blockIdx.x - 4096;
  const int z = wi >> 8, r8 = wi & 255;
  const int k0 = (r8 >> 4) * 64, n0 = (r8 & 15) * 64;
  const float* w = (z == 0) ? Wq : (z == 1) ? Wk : (z == 2) ? Wv : Wo;
  const float scale = (z == 0) ? QSCALE : 1.0f;
  u16* wt = wt_all + (size_t)z * Dn * Dn;
  #pragma unroll
  for (int i = 0; i < 4; i++){
    int idx = i*256 + t;
    int r = idx >> 4, c4 = (idx & 15) * 4;
    float4 f = *(const float4*)(w + (size_t)(k0 + r)*Dn + n0 + c4);
    tile[r*66 + c4 + 0] = f2bf(f.x * scale);
    tile[r*66 + c4 + 1] = f2bf(f.y * scale);
    tile[r*66 + c4 + 2] = f2bf(f.z * scale);
    tile[r*66 + c4 + 3] = f2bf(f.w * scale);
  }
  __syncthreads();
  #pragma unroll
  for (int i = 0; i < 4; i++){
    int idx = i*256 + t;
    int nr = idx >> 4, kc4 = (idx & 15) * 4;
    u16x4 o;
    o[0] = tile[(kc4+0)*66 + nr];
    o[1] = tile[(kc4+1)*66 + nr];
    o[2] = tile[(kc4+2)*66 + nr];
    o[3] = tile[(kc4+3)*66 + nr];
    *(u16x4*)(wt + (size_t)(n0 + nr)*Dn + k0 + kc4) = o;
  }
}

// ---------------- QKV GEMM: 256^2-tile, 8-phase counted-vmcnt schedule ----------------
// BM=BN=256, BK=64, 512 thr = 8 waves (2M x 4N), per-wave C = 128x64.
// LDS 128KB: 2 bufs x (A 256x64 + B 256x64) bf16. Halves of 128 rows are the
// stage unit (2 x global_load_lds dwordx4 per thread). LDS layout is XOR-
// swizzled per 16B granule: linear pos (row, g) holds logical granule
// g ^ (row&7)  -> pre-swizzled GLOBAL source + swizzled ds_read (T2; m201).
// Stage slots: ph1 -> (t+1, A-h1) [other buf]; ph2 -> (t+2, B-h0);
// ph3 -> (t+2, B-h1); ph4 -> (t+2, A-h0) [cur buf; slot read-free by then:
// B read only in ph1, A-h* last read in ph3, barriers between].
// vmcnt(6) once per K-tile at ph4 => drains exactly tile t+1's 4 halves,
// leaves t+2's 3 halves in flight (T4). Raw s_barrier (no vmcnt(0) drain);
// explicit lgkmcnt(0) after mid-barrier in read-phases so no ds_read is
// still in flight when a later stage DMA overwrites its slot.
#define MFMA_B16(d, va, vb) (d) = __builtin_amdgcn_mfma_f32_16x16x32_bf16((va), (vb), (d), 0, 0, 0)
#define BARRAW() __builtin_amdgcn_s_barrier()
#define WAIT_LGKM0() asm volatile("s_waitcnt lgkmcnt(0)" ::: "memory")
#define VM6() asm volatile("s_waitcnt vmcnt(6)" ::: "memory")
#define VM0() asm volatile("s_waitcnt vmcnt(0)" ::: "memory")
#define SCHEDB() __builtin_amdgcn_sched_barrier(0)

__launch_bounds__(512, 2)
__global__ void gemm_qkv_kernel(const u16* __restrict__ xb, const u16* __restrict__ wt_all,
                                u16* __restrict__ qb, u16* __restrict__ kb, u16* __restrict__ vtb){
  __shared__ u16 sm[65536];   // 128 KB
  const int t = threadIdx.x;
  const int lane = t & 63, wave = t >> 6;
  const int ln = lane & 15, quad = lane >> 4;
  const int wm = wave >> 2, wn = wave & 3;

  // T1: XCD-chunked bijective swizzle (384 = 8*48). n-fastest within chunk.
  const int lin = blockIdx.x;
  const int wg = (lin & 7) * 48 + (lin >> 3);
  const int zsel = wg >> 7;
  const int rem = wg & 127;
  const int m0 = (rem >> 2) * 256;
  const int n0 = (rem & 3) * 256;
  const u16* wt = wt_all + (size_t)zsel * Dn * Dn;

  // staging: idx in [0,1024), row=idx>>3, granule g=idx&7, src granule g^(row&7)
  const int r0 = t >> 3,      sg0 = (t & 7) ^ (r0 & 7);
  const int i1 = 512 + t;
  const int r1 = i1 >> 3,     sg1 = (i1 & 7) ^ (r1 & 7);
  const u16* ax0 = xb + (size_t)(m0 + r0)*Dn + sg0*8;
  const u16* ax1 = xb + (size_t)(m0 + r1)*Dn + sg1*8;
  const u16* bw0 = wt + (size_t)(n0 + r0)*Dn + sg0*8;
  const u16* bw1 = wt + (size_t)(n0 + r1)*Dn + sg1*8;
  const int ld0 = t*8, ld1 = 4096 + t*8;   // u16 offsets within a 128x64 half

#define STG_A(buf, h, tt) do { \
    G2L16(&sm[(buf)*32768 + (h)*8192 + ld0], ax0 + (size_t)(h)*128*Dn + (tt)*64); \
    G2L16(&sm[(buf)*32768 + (h)*8192 + ld1], ax1 + (size_t)(h)*128*Dn + (tt)*64); } while(0)
#define STG_B(buf, h, tt) do { \
    G2L16(&sm[(buf)*32768 + 16384 + (h)*8192 + ld0], bw0 + (size_t)(h)*128*Dn + (tt)*64); \
    G2L16(&sm[(buf)*32768 + 16384 + (h)*8192 + ld1], bw1 + (size_t)(h)*128*Dn + (tt)*64); } while(0)

  // swizzled ds_read offsets (u16 units; granule index bits 3-5 XOR row&7)
  const int swz = (ln & 7) * 8;
  const int ac0 = (quad*8) ^ swz;
  const int ac1 = (32 + quad*8) ^ swz;
  const int abase = wm*8192 + ln*64;
  const int bbase = 16384 + (wn>>1)*8192 + ((wn&1)*64 + ln)*64;

  f32x4 acc[8][4] = {};
  bf16x8 aq[4][2], bq[4][2];

  // prologue: tile0 all 4 halves, then 3 halves of tile1; drain to 6 => tile0 ready
  STG_B(0,0,0); STG_B(0,1,0); STG_A(0,0,0); STG_A(0,1,0);
  STG_B(1,0,1); STG_B(1,1,1); STG_A(1,0,1);
  VM6();
  BARRAW();

  for (int tp = 0; tp < 16; tp += 2){
    #pragma unroll
    for (int pi2 = 0; pi2 < 2; pi2++){
      const int tt = tp + pi2;
      const int cur = pi2;               // == tt&1 (tp even)
      const int nxt = cur ^ 1;
      const u16* bufp = &sm[cur*32768];

      // ---- phase 1: read A(mh0) + all B; stage (t+1, A-h1); MFMA quad (mh0,nh0)
      #pragma unroll
      for (int i = 0; i < 4; i++){
        aq[i][0] = *(const bf16x8*)&bufp[abase + i*1024 + ac0];
        aq[i][1] = *(const bf16x8*)&bufp[abase + i*1024 + ac1];
      }
      #pragma unroll
      for (int nf = 0; nf < 4; nf++){
        bq[nf][0] = *(const bf16x8*)&bufp[bbase + nf*1024 + ac0];
        bq[nf][1] = *(const bf16x8*)&bufp[bbase + nf*1024 + ac1];
      }
      SCHEDB();
      if (tt + 1 < 16) STG_A(nxt, 1, tt+1);
      BARRAW();
      WAIT_LGKM0();
      __builtin_amdgcn_s_setprio(1);
      #pragma unroll
      for (int i = 0; i < 4; i++)
        #pragma unroll
        for (int nf = 0; nf < 2; nf++){
          MFMA_B16(acc[i][nf], aq[i][0], bq[nf][0]);
          MFMA_B16(acc[i][nf], aq[i][1], bq[nf][1]);
        }
      __builtin_amdgcn_s_setprio(0);
      BARRAW();

      // ---- phase 2: stage (t+2, B-h0); MFMA quad (mh0,nh1)
      if (tt + 2 < 16) STG_B(cur, 0, tt+2);
      BARRAW();
      __builtin_amdgcn_s_setprio(1);
      #pragma unroll
      for (int i = 0; i < 4; i++)
        #pragma unroll
        for (int nf = 2; nf < 4; nf++){
          MFMA_B16(acc[i][nf], aq[i][0], bq[nf][0]);
          MFMA_B16(acc[i][nf], aq[i][1], bq[nf][1]);
        }
      __builtin_amdgcn_s_setprio(0);
      BARRAW();

      // ---- phase 3: read A(mh1); stage (t+2, B-h1); MFMA quad (mh1,nh1)
      #pragma unroll
      for (int i = 0; i < 4; i++){
        aq[i][0] = *(const bf16x8*)&bufp[abase + (4+i)*1024 + ac0];
        aq[i][1] = *(const bf16x8*)&bufp[abase + (4+i)*1024 + ac1];
      }
      SCHEDB();
      if (tt + 2 < 16) STG_B(cur, 1, tt+2);
      BARRAW();
      WAIT_LGKM0();
      __builtin_amdgcn_s_setprio(1);
      #pragma unroll
      for (int i = 0; i < 4; i++)
        #pragma unroll
        for (int nf = 2; nf < 4; nf++){
          MFMA_B16(acc[4+i][nf], aq[i][0], bq[nf][0]);
          MFMA_B16(acc[4+i][nf], aq[i][1], bq[nf][1]);
        }
      __builtin_amdgcn_s_setprio(0);
      BARRAW();

      // ---- phase 4: stage (t+2, A-h0); MFMA quad (mh1,nh0); counted vmcnt
      if (tt + 2 < 16) STG_A(cur, 0, tt+2);
      BARRAW();
      __builtin_amdgcn_s_setprio(1);
      #pragma unroll
      for (int i = 0; i < 4; i++)
        #pragma unroll
        for (int nf = 0; nf < 2; nf++){
          MFMA_B16(acc[4+i][nf], aq[i][0], bq[nf][0]);
          MFMA_B16(acc[4+i][nf], aq[i][1], bq[nf][1]);
        }
      __builtin_amdgcn_s_setprio(0);
      if (tt + 2 < 16) { VM6(); } else { VM0(); }
      BARRAW();
    }
  }

  // ---- epilogue: stage 128-row (or 128-col for Vt) slabs through LDS, pitch 264
  u16* Cs = sm;
  if (zsel < 2){
    u16* outp = (zsel == 0) ? qb : kb;
    #pragma unroll
    for (int round = 0; round < 2; round++){
      if (wm == round){
        #pragma unroll
        for (int mf = 0; mf < 8; mf++)
          #pragma unroll
          for (int nf = 0; nf < 4; nf++)
            #pragma unroll
            for (int reg = 0; reg < 4; reg++)
              Cs[(mf*16 + quad*4 + reg)*264 + wn*64 + nf*16 + ln] = f2bf(acc[mf][nf][reg]);
      }
      __syncthreads();
      #pragma unroll
      for (int it = 0; it < 8; it++){
        int idx = it*512 + t;
        int r = idx >> 5, c8 = (idx & 31) * 8;
        bf16x8 vdat = *(const bf16x8*)&Cs[r*264 + c8];
        int row = m0 + round*128 + r, bb = row >> 11, s = row & 2047;
        int col = n0 + c8, hh = col >> 6, d = col & 63;
        *(bf16x8*)(outp + (((size_t)bb*Hn + hh)*Sn + s)*DHn + d) = vdat;
      }
      if (round == 0) __syncthreads();
    }
  } else {
    #pragma unroll
    for (int round = 0; round < 2; round++){
      if ((wn >> 1) == round){
        #pragma unroll
        for (int mf = 0; mf < 8; mf++)
          #pragma unroll
          for (int nf = 0; nf < 4; nf++){
            u16x4 o;
            #pragma unroll
            for (int reg = 0; reg < 4; reg++) o[reg] = f2bf(acc[mf][nf][reg]);
            *(u16x4*)&Cs[((wn&1)*64 + nf*16 + ln)*264 + wm*128 + mf*16 + quad*4] = o;
          }
      }
      __syncthreads();
      #pragma unroll
      for (int it = 0; it < 8; it++){
        int idx = it*512 + t;
        int r = idx >> 5, c8 = (idx & 31) * 8;
        bf16x8 vdat = *(const bf16x8*)&Cs[r*264 + c8];
        int col = n0 + round*128 + r, hh = col >> 6, d = col & 63;
        int row = m0 + c8, bb = row >> 11, s = row & 2047;
        *(bf16x8*)(vtb + (((size_t)bb*Hn + hh)*DHn + d)*Sn + s) = vdat;
      }
      if (round == 0) __syncthreads();
    }
  }
}

// ---------------- attention: S^T formulation, 64 q/wave, pipelined, ks-split ----------------
// Unchanged compute; added XCD-chunked swizzle so all 8 q-tiles of one (b,h)
// share one XCD's L2 (K/V ~0.5MB per head).
__launch_bounds__(256, 2)
__global__ void attn_kernel(const u16* q, const u16* __restrict__ k,
                            const u16* __restrict__ vt, u16* z){
  __shared__ u16 Ks[2][64*72];   // [key][d]
  __shared__ u16 Vs[2][64*72];   // [d][key'] column-shuffled: col'=ks*32+quad*8+j
  const int t = threadIdx.x;
  const int wave = t >> 6, lane = t & 63;
  const int ln = lane & 15, quad = lane >> 4;
  const int lin = blockIdx.x + 8*(blockIdx.y + 16*blockIdx.z);
  const int wgs = (lin & 7)*64 + (lin >> 3);
  const int qt = wgs & 7, h = (wgs >> 3) & 15, b = wgs >> 7;
  const size_t bh = (size_t)b * Hn + h;
  const int q0 = qt*256 + wave*64;
  const u16* qp = q + bh * Sn * DHn;
  const u16* kp = k + bh * Sn * DHn;
  const u16* vp = vt + bh * DHn * Sn;

  bf16x8 qf[4][2];
  #pragma unroll
  for (int n = 0; n < 4; n++)
    #pragma unroll
    for (int kq = 0; kq < 2; kq++)
      qf[n][kq] = *(const bf16x8*)(qp + (size_t)(q0 + n*16 + ln)*DHn + kq*32 + quad*8);

  f32x4 zacc[4][4] = {};
  float dacc[4] = {0.f, 0.f, 0.f, 0.f};

  int sr[2], sc[2], vc1[2], vc2[2];
  #pragma unroll
  for (int i = 0; i < 2; i++){
    int idx = i*256 + t, r = idx >> 3, a = idx & 7;
    sr[i] = r; sc[i] = a*8;
    int ksg = a >> 2, q1 = ((a&3)*2)&3, h1 = (a&3) >> 1;
    vc1[i] = ksg*32 + q1*8 + h1*4;
    vc2[i] = ksg*32 + (((q1+1)&3))*8 + h1*4;
  }

  bf16x8 rk[2], rv[2];
  #pragma unroll
  for (int i = 0; i < 2; i++){
    rk[i] = *(const bf16x8*)(kp + (size_t)sr[i]*DHn + sc[i]);
    rv[i] = *(const bf16x8*)(vp + (size_t)sr[i]*Sn + sc[i]);
  }
  #pragma unroll
  for (int i = 0; i < 2; i++){
    *(bf16x8*)&Ks[0][sr[i]*72 + sc[i]] = rk[i];
    u16x4 lo = *(u16x4*)&rv[i];
    u16x4 hi = *((u16x4*)&rv[i] + 1);
    *(u16x4*)&Vs[0][sr[i]*72 + vc1[i]] = lo;
    *(u16x4*)&Vs[0][sr[i]*72 + vc2[i]] = hi;
  }

  for (int kt = 0; kt < Sn/64; kt++){
    const int cur = kt & 1;
    __syncthreads();

    if (kt + 1 < Sn/64){
      #pragma unroll
      for (int i = 0; i < 2; i++){
        rk[i] = *(const bf16x8*)(kp + (size_t)((kt+1)*64 + sr[i])*DHn + sc[i]);
        rv[i] = *(const bf16x8*)(vp + (size_t)sr[i]*Sn + (kt+1)*64 + sc[i]);
      }
    }
    const u16* Kc = Ks[cur];
    const u16* Vc = Vs[cur];

    #pragma unroll
    for (int ks = 0; ks < 2; ks++){
      f32x4 sacc[2][4] = {};
      #pragma unroll
      for (int kq = 0; kq < 2; kq++){
        bf16x8 ka[2];
        #pragma unroll
        for (int m2 = 0; m2 < 2; m2++)
          ka[m2] = *(const bf16x8*)&Kc[((2*ks + m2)*16 + ln)*72 + kq*32 + quad*8];
        #pragma unroll
        for (int m2 = 0; m2 < 2; m2++)
          #pragma unroll
          for (int n = 0; n < 4; n++)
            sacc[m2][n] = __builtin_amdgcn_mfma_f32_16x16x32_bf16(ka[m2], qf[n][kq], sacc[m2][n], 0, 0, 0);
      }
      B8 pb[4];
      #pragma unroll
      for (int n = 0; n < 4; n++){
        f32x4 s0 = sacc[0][n], s1 = sacc[1][n];
        float a0 = EXP2(s0[0]), a1 = EXP2(s0[1]), a2 = EXP2(s0[2]), a3 = EXP2(s0[3]);
        float b0 = EXP2(s1[0]), b1 = EXP2(s1[1]), b2 = EXP2(s1[2]), b3 = EXP2(s1[3]);
        dacc[n] += ((a0 + a1) + (a2 + a3)) + ((b0 + b1) + (b2 + b3));
        pb[n].u = (u32x4){pack_bf2(a0, a1), pack_bf2(a2, a3), pack_bf2(b0, b1), pack_bf2(b2, b3)};
      }
      #pragma unroll
      for (int mtd = 0; mtd < 4; mtd++){
        bf16x8 va = *(const bf16x8*)&Vc[(mtd*16 + ln)*72 + ks*32 + quad*8];
        #pragma unroll
        for (int n = 0; n < 4; n++)
          zacc[mtd][n] = __builtin_amdgcn_mfma_f32_16x16x32_bf16(va, pb[n].s, zacc[mtd][n], 0, 0, 0);
      }
    }

    if (kt + 1 < Sn/64){
      const int nxt = (kt+1) & 1;
      #pragma unroll
      for (int i = 0; i < 2; i++){
        *(bf16x8*)&Ks[nxt][sr[i]*72 + sc[i]] = rk[i];
        u16x4 lo = *(u16x4*)&rv[i];
        u16x4 hi = *((u16x4*)&rv[i] + 1);
        *(u16x4*)&Vs[nxt][sr[i]*72 + vc1[i]] = lo;
        *(u16x4*)&Vs[nxt][sr[i]*72 + vc2[i]] = hi;
      }
    }
  }

  float inv[4];
  #pragma unroll
  for (int n = 0; n < 4; n++){
    float d = dacc[n];
    d += __shfl_xor(d, 16, 64);
    d += __shfl_xor(d, 32, 64);
    inv[n] = 1.0f / d;
  }

  #pragma unroll
  for (int mtd = 0; mtd < 4; mtd++)
    #pragma unroll
    for (int n = 0; n < 4; n++){
      u16x4 o;
      #pragma unroll
      for (int j = 0; j < 4; j++) o[j] = f2bf(zacc[mtd][n][j] * inv[n]);
      *(u16x4*)(z + (bh*Sn + (size_t)(q0 + n*16 + ln))*DHn + mtd*16 + quad*4) = o;
    }
}

// ---------------- out = z * Wout^T + x  (fp32 out), BK=64 single-barrier dbuf ----------------
// K-chunk of 64 == exactly one head of z: ki = head, sub*32 = d-offset.
// Added XCD-chunked swizzle (512 = 8*64), n-fastest within chunk.
__launch_bounds__(256)
__global__ void gemm_out_kernel(const u16* __restrict__ zb, const u16* __restrict__ wt,
                                const float* __restrict__ x, float* __restrict__ out){
  __shared__ u16 smem[32768];   // 64 KB: 2 stages x (A0 B0 A1 B1)
  const int t = threadIdx.x;
  const int wave = t >> 6, lane = t & 63;
  const int ln = lane & 15, quad = lane >> 4;
  const int wm = wave >> 1, wn = wave & 1;
  const int lin = blockIdx.y * 8 + blockIdx.x;
  const int wgs = (lin & 7)*64 + (lin >> 3);
  const int n0 = (wgs & 7) * 128;
  const int m0 = (wgs >> 3) * 128;

  f32x4 acc[4][4] = {};

  #pragma unroll
  for (int sub = 0; sub < 2; sub++)
    #pragma unroll
    for (int i = 0; i < 2; i++){
      int idx = i*256 + t;
      int r = idx >> 2, c8 = (idx & 3) * 8;
      int row = m0 + r, bb = row >> 11, s = row & 2047;
      G2L16(&smem[sub*8192 + idx*8],        zb + (((size_t)bb*Hn + 0)*Sn + s)*DHn + sub*32 + c8);
      G2L16(&smem[sub*8192 + 4096 + idx*8], wt + (size_t)(n0 + r)*Dn + sub*32 + c8);
    }

  for (int ki = 0; ki < 16; ki++){
    const int cur = ki & 1;
    __syncthreads();
    if (ki + 1 < 16){
      const int nxt = 16384 * ((ki+1) & 1);
      const int hh = ki + 1;           // 64-K chunk == head hh, d0 = sub*32
      const int kt = (ki+1) * 64;
      #pragma unroll
      for (int sub = 0; sub < 2; sub++)
        #pragma unroll
        for (int i = 0; i < 2; i++){
          int idx = i*256 + t;
          int r = idx >> 2, c8 = (idx & 3) * 8;
          int row = m0 + r, bb = row >> 11, s = row & 2047;
          G2L16(&smem[nxt + sub*8192 + idx*8],        zb + (((size_t)bb*Hn + hh)*Sn + s)*DHn + sub*32 + c8);
          G2L16(&smem[nxt + sub*8192 + 4096 + idx*8], wt + (size_t)(n0 + r)*Dn + kt + sub*32 + c8);
        }
    }
    #pragma unroll
    for (int sub = 0; sub < 2; sub++){
      const u16* As = &smem[16384*cur + sub*8192];
      const u16* Bs = As + 4096;
      bf16x8 a[4], b[4];
      #pragma unroll
      for (int rb = 0; rb < 4; rb++) a[rb] = *(const bf16x8*)&As[(wm*64 + rb*16 + ln)*32 + quad*8];
      #pragma unroll
      for (int cb = 0; cb < 4; cb++) b[cb] = *(const bf16x8*)&Bs[(wn*64 + cb*16 + ln)*32 + quad*8];
      #pragma unroll
      for (int rb = 0; rb < 4; rb++)
        #pragma unroll
        for (int cb = 0; cb < 4; cb++)
          acc[rb][cb] = __builtin_amdgcn_mfma_f32_16x16x32_bf16(a[rb], b[cb], acc[rb][cb], 0, 0, 0);
    }
  }

  #pragma unroll
  for (int rb = 0; rb < 4; rb++)
    #pragma unroll
    for (int cb = 0; cb < 4; cb++)
      #pragma unroll
      for (int reg = 0; reg < 4; reg++){
        int row = m0 + wm*64 + rb*16 + quad*4 + reg;
        int col = n0 + wn*64 + cb*16 + ln;
        size_t off = (size_t)row*Dn + col;
        out[off] = acc[rb][cb][reg] + x[off];
      }
}

extern "C" void kernel_launch(void* const* d_in, const int* in_sizes, int n_in,
                              void* d_out, int out_size, void* d_ws, size_t ws_size,
                              hipStream_t stream){
  const float* x    = (const float*)d_in[0];
  const float* Wq   = (const float*)d_in[2];
  const float* Wk   = (const float*)d_in[3];
  const float* Wv   = (const float*)d_in[4];
  const float* Wout = (const float*)d_in[5];
  float* out = (float*)d_out;

  u16* ws = (u16*)d_ws;
  const size_t NW = (size_t)Dn * Dn;
  const size_t NX = (size_t)Bn * Sn * Dn;
  u16* wt  = ws;                // Wq^T(scaled),Wk^T,Wv^T,Wout^T
  u16* xb  = wt + 4*NW;         // x bf16
  u16* qb  = xb + NX;           // Q [b,h,s,d] (attn writes z in-place)
  u16* kb  = qb + NX;           // K [b,h,s,d]
  u16* vtb = kb + NX;           // Vt [b,h,d,s] (written directly by gemm_qkv)

  prep_kernel     <<<dim3(4096 + 1024), dim3(256), 0, stream>>>(x, Wq, Wk, Wv, Wout, xb, wt);
  gemm_qkv_kernel <<<dim3(384), dim3(512), 0, stream>>>(xb, wt, qb, kb, vtb);
  attn_kernel     <<<dim3(8,16,4), dim3(256), 0, stream>>>(qb, kb, vtb, qb);
  gemm_out_kernel <<<dim3(8,64), dim3(256), 0, stream>>>(qb, wt + 3*NW, x, out);
}

// Round 2
// 255.169 us; speedup vs baseline: 1.0935x; 1.0333x over previous
//
#include <hip/hip_runtime.h>

#define Bn 4
#define Sn 2048
#define Dn 1024
#define Hn 16
#define DHn 64

typedef float f32x4 __attribute__((ext_vector_type(4)));
typedef short bf16x8 __attribute__((ext_vector_type(8)));
typedef unsigned short u16;
typedef unsigned int u32;
typedef unsigned short u16x8 __attribute__((ext_vector_type(8)));
typedef unsigned short u16x4 __attribute__((ext_vector_type(4)));
typedef u32 u32x4 __attribute__((ext_vector_type(4)));

union B8 { u32x4 u; bf16x8 s; u16x8 h; };

__device__ __forceinline__ u16 f2bf(float f){
  union { float f; u32 u; } v; v.f = f;
  return (u16)((v.u + 0x7fffu + ((v.u >> 16) & 1u)) >> 16);
}

// truncating pack: two fp32 -> {bf16(lo) | bf16(hi)<<16}. P>0 -> -0.2% uniform bias, negligible.
__device__ __forceinline__ u32 pack_bf2(float lo, float hi){
  union { float f; u32 u; } a, b;
  a.f = lo; b.f = hi;
  return __builtin_amdgcn_perm(b.u, a.u, 0x07060302u);
}

#if __has_builtin(__builtin_amdgcn_exp2f)
#define EXP2(x) __builtin_amdgcn_exp2f(x)
#define QSCALE 0.18033688011112042f   /* 0.125 * log2(e) */
#else
#define EXP2(x) __expf(x)
#define QSCALE 0.125f
#endif

#if __has_builtin(__builtin_amdgcn_global_load_lds)
#define G2L16(l, g) __builtin_amdgcn_global_load_lds((const __attribute__((address_space(1))) u32*)(g), \
                                                     (__attribute__((address_space(3))) u32*)(l), 16, 0, 0)
#else
#define G2L16(l, g) (*(bf16x8*)(l) = *(const bf16x8*)(g))
#endif

#define MFMA_B16(d, va, vb) (d) = __builtin_amdgcn_mfma_f32_16x16x32_bf16((va), (vb), (d), 0, 0, 0)
#define BARRAW() __builtin_amdgcn_s_barrier()
#define WAIT_LGKM0() asm volatile("s_waitcnt lgkmcnt(0)" ::: "memory")
#define VM4() asm volatile("s_waitcnt vmcnt(4)" ::: "memory")
#define VM0() asm volatile("s_waitcnt vmcnt(0)" ::: "memory")
#define SCHEDB() __builtin_amdgcn_sched_barrier(0)

// ---------------- merged prep: cast x (blocks 0..4095) + 4 weights (4096..5119) ----------------
__global__ void prep_kernel(const float* __restrict__ x,
                            const float* __restrict__ Wq, const float* __restrict__ Wk,
                            const float* __restrict__ Wv, const float* __restrict__ Wo,
                            u16* __restrict__ xb, u16* __restrict__ wt_all){
  __shared__ u16 tile[64*66];
  const int t = threadIdx.x;
  if (blockIdx.x < 4096){
    size_t i = ((size_t)blockIdx.x * 256 + t) * 8;
    float4 f0 = *(const float4*)(x + i);
    float4 f1 = *(const float4*)(x + i + 4);
    u16x8 o;
    o[0]=f2bf(f0.x); o[1]=f2bf(f0.y); o[2]=f2bf(f0.z); o[3]=f2bf(f0.w);
    o[4]=f2bf(f1.x); o[5]=f2bf(f1.y); o[6]=f2bf(f1.z); o[7]=f2bf(f1.w);
    *(u16x8*)(xb + i) = o;
    return;
  }
  const int wi = blockIdx.x - 4096;
  const int z = wi >> 8, r8 = wi & 255;
  const int k0 = (r8 >> 4) * 64, n0 = (r8 & 15) * 64;
  const float* w = (z == 0) ? Wq : (z == 1) ? Wk : (z == 2) ? Wv : Wo;
  const float scale = (z == 0) ? QSCALE : 1.0f;
  u16* wt = wt_all + (size_t)z * Dn * Dn;
  #pragma unroll
  for (int i = 0; i < 4; i++){
    int idx = i*256 + t;
    int r = idx >> 4, c4 = (idx & 15) * 4;
    float4 f = *(const float4*)(w + (size_t)(k0 + r)*Dn + n0 + c4);
    tile[r*66 + c4 + 0] = f2bf(f.x * scale);
    tile[r*66 + c4 + 1] = f2bf(f.y * scale);
    tile[r*66 + c4 + 2] = f2bf(f.z * scale);
    tile[r*66 + c4 + 3] = f2bf(f.w * scale);
  }
  __syncthreads();
  #pragma unroll
  for (int i = 0; i < 4; i++){
    int idx = i*256 + t;
    int nr = idx >> 4, kc4 = (idx & 15) * 4;
    u16x4 o;
    o[0] = tile[(kc4+0)*66 + nr];
    o[1] = tile[(kc4+1)*66 + nr];
    o[2] = tile[(kc4+2)*66 + nr];
    o[3] = tile[(kc4+3)*66 + nr];
    *(u16x4*)(wt + (size_t)(n0 + nr)*Dn + k0 + kc4) = o;
  }
}

// ---------------- QKV GEMM: 128^2 tile, BK=64, A-tri/B-dbuf, 1 barrier/K-tile ----------------
// 256 thr = 4 waves (2x2), per-wave C = 64x64 (r0-proven fragment geometry).
// LDS 80KB: A x3 @ {0,8192,16384} (16KB each, tile t in buf t%3),
//           B x2 @ {24576,32768}  (tile t in buf t&1).  -> 2 blocks/CU (160KB exact).
// Tiles are [128 rows][64 cols] bf16, rows linear; 16B granule g of row r holds
// logical granule g^(r&7) (T2 XOR swizzle via pre-swizzled GLOBAL source + swizzled ds_read).
// Per K-tile: ONE raw s_barrier. Schedule (issue order fixed for vmcnt math):
//   phA(t): VM4 (t<15; else VM0); BAR; ds_read a(rows 0-31)+all b; STGB B(t+1); lgkm0; 16 MFMA
//   phB(t): ds_read a(rows 32-63); STGA A(t+2); lgkm0; 16 MFMA
// vmcnt(4) at phA(t) drains A(t) (issued phB(t-2), ~1.5-tile cover) and B(t)
// (issued phA(t-1), 1-tile cover), leaves A(t+1)'s 4 loads in flight (never 0).
// Slot safety: every slot's last reader passed its lgkm0 before the barrier
// preceding the overwrite (b_cur(t) overwritten phA(t+1) after BAR(t+1); a_cur(t)
// overwritten phB(t+1) after BAR(t+1)).
__launch_bounds__(256)
__global__ void gemm_qkv_kernel(const u16* __restrict__ xb, const u16* __restrict__ wt_all,
                                u16* __restrict__ qb, u16* __restrict__ kb, u16* __restrict__ vtb){
  __shared__ u16 sm[40960];   // 80 KB
  const int t = threadIdx.x;
  const int lane = t & 63, wave = t >> 6;
  const int ln = lane & 15, quad = lane >> 4;
  const int wm = wave >> 1, wn = wave & 1;

  // T1: XCD-chunked bijective swizzle (1536 = 8*192), m-outer n-inner within chunk
  // (B panel 2MB stays L2-resident per XCD; A streamed once).
  const int lin = blockIdx.x;
  const int wg = (lin & 7) * 192 + (lin >> 3);
  const int zsel = wg >> 9;
  const int rem = wg & 511;
  const int m0 = (rem >> 3) * 128;
  const int n0 = (rem & 7) * 128;
  const u16* wt = wt_all + (size_t)zsel * Dn * Dn;

  // staging: 1024 granules per 128x64 tile, 4 per thread; src granule pre-swizzled
  const u16* ap[4]; const u16* bp[4]; int ldo[4];
  #pragma unroll
  for (int p = 0; p < 4; p++){
    int idx = p*256 + t;
    int r = idx >> 3, g = (idx & 7) ^ (r & 7);
    ap[p] = xb + (size_t)(m0 + r)*Dn + g*8;
    bp[p] = wt + (size_t)(n0 + r)*Dn + g*8;
    ldo[p] = idx * 8;
  }
#define STGA(buf, tt) do { _Pragma("unroll") for (int p = 0; p < 4; p++) \
    G2L16(&sm[(buf) + ldo[p]], ap[p] + (size_t)(tt)*64); } while(0)
#define STGB(buf, tt) do { _Pragma("unroll") for (int p = 0; p < 4; p++) \
    G2L16(&sm[(buf) + ldo[p]], bp[p] + (size_t)(tt)*64); } while(0)

  // swizzled ds_read offsets (u16 units): granule (kq*4+quad) ^ (ln&7)
  const int agr0 = ((    quad) ^ (ln & 7)) * 8;
  const int agr1 = ((4 + quad) ^ (ln & 7)) * 8;
  int arow[4], brow[4];
  #pragma unroll
  for (int i = 0; i < 4; i++) arow[i] = (wm*64 + i*16 + ln) * 64;
  #pragma unroll
  for (int j = 0; j < 4; j++) brow[j] = (wn*64 + j*16 + ln) * 64;

  f32x4 acc[4][4] = {};

  // prologue: A(0)->a0, B(0)->b0, A(1)->a1  (12 loads in flight)
  STGA(0, 0); STGB(24576, 0); STGA(8192, 1);

  #pragma unroll
  for (int tt = 0; tt < 16; ++tt){
    const int a_cur = (tt % 3) * 8192;
    const int a_pf  = ((tt + 2) % 3) * 8192;
    const int b_cur = 24576 + (tt & 1) * 8192;
    const int b_pf  = 24576 + ((tt + 1) & 1) * 8192;

    if (tt < 15) { VM4(); } else { VM0(); }
    BARRAW(); SCHEDB();

    // ---- phA: rows 0-31 of this wave's A band + all B
    bf16x8 a01[2][2], bq[4][2];
    #pragma unroll
    for (int i = 0; i < 2; i++){
      a01[i][0] = *(const bf16x8*)&sm[a_cur + arow[i] + agr0];
      a01[i][1] = *(const bf16x8*)&sm[a_cur + arow[i] + agr1];
    }
    #pragma unroll
    for (int j = 0; j < 4; j++){
      bq[j][0] = *(const bf16x8*)&sm[b_cur + brow[j] + agr0];
      bq[j][1] = *(const bf16x8*)&sm[b_cur + brow[j] + agr1];
    }
    SCHEDB();
    if (tt < 15) STGB(b_pf, tt + 1);
    SCHEDB();
    WAIT_LGKM0(); SCHEDB();
    __builtin_amdgcn_s_setprio(1);
    #pragma unroll
    for (int i = 0; i < 2; i++)
      #pragma unroll
      for (int j = 0; j < 4; j++){
        MFMA_B16(acc[i][j], a01[i][0], bq[j][0]);
        MFMA_B16(acc[i][j], a01[i][1], bq[j][1]);
      }
    __builtin_amdgcn_s_setprio(0);

    // ---- phB: rows 32-63
    bf16x8 a23[2][2];
    #pragma unroll
    for (int i = 0; i < 2; i++){
      a23[i][0] = *(const bf16x8*)&sm[a_cur + arow[2+i] + agr0];
      a23[i][1] = *(const bf16x8*)&sm[a_cur + arow[2+i] + agr1];
    }
    SCHEDB();
    if (tt < 14) STGA(a_pf, tt + 2);
    SCHEDB();
    WAIT_LGKM0(); SCHEDB();
    __builtin_amdgcn_s_setprio(1);
    #pragma unroll
    for (int i = 0; i < 2; i++)
      #pragma unroll
      for (int j = 0; j < 4; j++){
        MFMA_B16(acc[2+i][j], a23[i][0], bq[j][0]);
        MFMA_B16(acc[2+i][j], a23[i][1], bq[j][1]);
      }
    __builtin_amdgcn_s_setprio(0);
  }

  __syncthreads();
  // ---- epilogue (r0-proven): C 128x128 through LDS, pitch 136
  u16* Cs = sm;
  if (zsel < 2){
    u16* outp = (zsel == 0) ? qb : kb;
    #pragma unroll
    for (int rb = 0; rb < 4; rb++)
      #pragma unroll
      for (int cb = 0; cb < 4; cb++)
        #pragma unroll
        for (int reg = 0; reg < 4; reg++)
          Cs[(wm*64 + rb*16 + quad*4 + reg)*136 + wn*64 + cb*16 + ln] = f2bf(acc[rb][cb][reg]);
    __syncthreads();
    #pragma unroll
    for (int i = 0; i < 8; i++){
      int idx = i*256 + t;
      int r = idx >> 4, c8 = (idx & 15) * 8;
      bf16x8 vdat = *(const bf16x8*)&Cs[r*136 + c8];
      int row = m0 + r, bb = row >> 11, s = row & 2047;
      int col = n0 + c8, hh = col >> 6, d = col & 63;
      *(bf16x8*)(outp + (((size_t)bb*Hn + hh)*Sn + s)*DHn + d) = vdat;
    }
  } else {
    #pragma unroll
    for (int rb = 0; rb < 4; rb++)
      #pragma unroll
      for (int cb = 0; cb < 4; cb++){
        u16x4 o;
        #pragma unroll
        for (int reg = 0; reg < 4; reg++) o[reg] = f2bf(acc[rb][cb][reg]);
        *(u16x4*)&Cs[(wn*64 + cb*16 + ln)*136 + wm*64 + rb*16 + quad*4] = o;
      }
    __syncthreads();
    #pragma unroll
    for (int i = 0; i < 8; i++){
      int idx = i*256 + t;
      int c = idx >> 4, r8 = (idx & 15) * 8;
      bf16x8 vdat = *(const bf16x8*)&Cs[c*136 + r8];
      int col = n0 + c, hh = col >> 6, d = col & 63;
      int row = m0 + r8, bb = row >> 11, s = row & 2047;
      *(bf16x8*)(vtb + (((size_t)bb*Hn + hh)*DHn + d)*Sn + s) = vdat;
    }
  }
#undef STGA
#undef STGB
}

// ---------------- attention: S^T formulation, 64 q/wave, pipelined, ks-split ----------------
// Unchanged compute; XCD-chunked swizzle so all 8 q-tiles of one (b,h) share one XCD's L2.
__launch_bounds__(256, 2)
__global__ void attn_kernel(const u16* q, const u16* __restrict__ k,
                            const u16* __restrict__ vt, u16* z){
  __shared__ u16 Ks[2][64*72];   // [key][d]
  __shared__ u16 Vs[2][64*72];   // [d][key'] column-shuffled: col'=ks*32+quad*8+j
  const int t = threadIdx.x;
  const int wave = t >> 6, lane = t & 63;
  const int ln = lane & 15, quad = lane >> 4;
  const int lin = blockIdx.x + 8*(blockIdx.y + 16*blockIdx.z);
  const int wgs = (lin & 7)*64 + (lin >> 3);
  const int qt = wgs & 7, h = (wgs >> 3) & 15, b = wgs >> 7;
  const size_t bh = (size_t)b * Hn + h;
  const int q0 = qt*256 + wave*64;
  const u16* qp = q + bh * Sn * DHn;
  const u16* kp = k + bh * Sn * DHn;
  const u16* vp = vt + bh * DHn * Sn;

  bf16x8 qf[4][2];
  #pragma unroll
  for (int n = 0; n < 4; n++)
    #pragma unroll
    for (int kq = 0; kq < 2; kq++)
      qf[n][kq] = *(const bf16x8*)(qp + (size_t)(q0 + n*16 + ln)*DHn + kq*32 + quad*8);

  f32x4 zacc[4][4] = {};
  float dacc[4] = {0.f, 0.f, 0.f, 0.f};

  int sr[2], sc[2], vc1[2], vc2[2];
  #pragma unroll
  for (int i = 0; i < 2; i++){
    int idx = i*256 + t, r = idx >> 3, a = idx & 7;
    sr[i] = r; sc[i] = a*8;
    int ksg = a >> 2, q1 = ((a&3)*2)&3, h1 = (a&3) >> 1;
    vc1[i] = ksg*32 + q1*8 + h1*4;
    vc2[i] = ksg*32 + (((q1+1)&3))*8 + h1*4;
  }

  bf16x8 rk[2], rv[2];
  #pragma unroll
  for (int i = 0; i < 2; i++){
    rk[i] = *(const bf16x8*)(kp + (size_t)sr[i]*DHn + sc[i]);
    rv[i] = *(const bf16x8*)(vp + (size_t)sr[i]*Sn + sc[i]);
  }
  #pragma unroll
  for (int i = 0; i < 2; i++){
    *(bf16x8*)&Ks[0][sr[i]*72 + sc[i]] = rk[i];
    u16x4 lo = *(u16x4*)&rv[i];
    u16x4 hi = *((u16x4*)&rv[i] + 1);
    *(u16x4*)&Vs[0][sr[i]*72 + vc1[i]] = lo;
    *(u16x4*)&Vs[0][sr[i]*72 + vc2[i]] = hi;
  }

  for (int kt = 0; kt < Sn/64; kt++){
    const int cur = kt & 1;
    __syncthreads();

    if (kt + 1 < Sn/64){
      #pragma unroll
      for (int i = 0; i < 2; i++){
        rk[i] = *(const bf16x8*)(kp + (size_t)((kt+1)*64 + sr[i])*DHn + sc[i]);
        rv[i] = *(const bf16x8*)(vp + (size_t)sr[i]*Sn + (kt+1)*64 + sc[i]);
      }
    }
    const u16* Kc = Ks[cur];
    const u16* Vc = Vs[cur];

    #pragma unroll
    for (int ks = 0; ks < 2; ks++){
      f32x4 sacc[2][4] = {};
      #pragma unroll
      for (int kq = 0; kq < 2; kq++){
        bf16x8 ka[2];
        #pragma unroll
        for (int m2 = 0; m2 < 2; m2++)
          ka[m2] = *(const bf16x8*)&Kc[((2*ks + m2)*16 + ln)*72 + kq*32 + quad*8];
        #pragma unroll
        for (int m2 = 0; m2 < 2; m2++)
          #pragma unroll
          for (int n = 0; n < 4; n++)
            sacc[m2][n] = __builtin_amdgcn_mfma_f32_16x16x32_bf16(ka[m2], qf[n][kq], sacc[m2][n], 0, 0, 0);
      }
      B8 pb[4];
      #pragma unroll
      for (int n = 0; n < 4; n++){
        f32x4 s0 = sacc[0][n], s1 = sacc[1][n];
        float a0 = EXP2(s0[0]), a1 = EXP2(s0[1]), a2 = EXP2(s0[2]), a3 = EXP2(s0[3]);
        float b0 = EXP2(s1[0]), b1 = EXP2(s1[1]), b2 = EXP2(s1[2]), b3 = EXP2(s1[3]);
        dacc[n] += ((a0 + a1) + (a2 + a3)) + ((b0 + b1) + (b2 + b3));
        pb[n].u = (u32x4){pack_bf2(a0, a1), pack_bf2(a2, a3), pack_bf2(b0, b1), pack_bf2(b2, b3)};
      }
      #pragma unroll
      for (int mtd = 0; mtd < 4; mtd++){
        bf16x8 va = *(const bf16x8*)&Vc[(mtd*16 + ln)*72 + ks*32 + quad*8];
        #pragma unroll
        for (int n = 0; n < 4; n++)
          zacc[mtd][n] = __builtin_amdgcn_mfma_f32_16x16x32_bf16(va, pb[n].s, zacc[mtd][n], 0, 0, 0);
      }
    }

    if (kt + 1 < Sn/64){
      const int nxt = (kt+1) & 1;
      #pragma unroll
      for (int i = 0; i < 2; i++){
        *(bf16x8*)&Ks[nxt][sr[i]*72 + sc[i]] = rk[i];
        u16x4 lo = *(u16x4*)&rv[i];
        u16x4 hi = *((u16x4*)&rv[i] + 1);
        *(u16x4*)&Vs[nxt][sr[i]*72 + vc1[i]] = lo;
        *(u16x4*)&Vs[nxt][sr[i]*72 + vc2[i]] = hi;
      }
    }
  }

  float inv[4];
  #pragma unroll
  for (int n = 0; n < 4; n++){
    float d = dacc[n];
    d += __shfl_xor(d, 16, 64);
    d += __shfl_xor(d, 32, 64);
    inv[n] = 1.0f / d;
  }

  #pragma unroll
  for (int mtd = 0; mtd < 4; mtd++)
    #pragma unroll
    for (int n = 0; n < 4; n++){
      u16x4 o;
      #pragma unroll
      for (int j = 0; j < 4; j++) o[j] = f2bf(zacc[mtd][n][j] * inv[n]);
      *(u16x4*)(z + (bh*Sn + (size_t)(q0 + n*16 + ln))*DHn + mtd*16 + quad*4) = o;
    }
}

// ---------------- out = z * Wout^T + x: same A-tri/B-dbuf template, K-chunk 64 == head ----------------
// 512 blocks, 2/CU -> all co-resident in ONE round.
__launch_bounds__(256)
__global__ void gemm_out_kernel(const u16* __restrict__ zb, const u16* __restrict__ wt,
                                const float* __restrict__ x, float* __restrict__ out){
  __shared__ u16 sm[40960];   // 80 KB
  const int t = threadIdx.x;
  const int lane = t & 63, wave = t >> 6;
  const int ln = lane & 15, quad = lane >> 4;
  const int wm = wave >> 1, wn = wave & 1;

  const int lin = blockIdx.x;
  const int wg = (lin & 7) * 64 + (lin >> 3);
  const int m0 = (wg >> 3) * 128;
  const int n0 = (wg & 7) * 128;

  const u16* ap[4]; const u16* bp[4]; int ldo[4];
  #pragma unroll
  for (int p = 0; p < 4; p++){
    int idx = p*256 + t;
    int r = idx >> 3, g = (idx & 7) ^ (r & 7);
    int row = m0 + r, bb = row >> 11, s = row & 2047;
    ap[p] = zb + ((size_t)bb*Hn*Sn + s)*DHn + g*8;    // head-0 base; head stride Sn*DHn
    bp[p] = wt + (size_t)(n0 + r)*Dn + g*8;
    ldo[p] = idx * 8;
  }
#define STGA(buf, tt) do { _Pragma("unroll") for (int p = 0; p < 4; p++) \
    G2L16(&sm[(buf) + ldo[p]], ap[p] + (size_t)(tt)*Sn*DHn); } while(0)
#define STGB(buf, tt) do { _Pragma("unroll") for (int p = 0; p < 4; p++) \
    G2L16(&sm[(buf) + ldo[p]], bp[p] + (size_t)(tt)*64); } while(0)

  const int agr0 = ((    quad) ^ (ln & 7)) * 8;
  const int agr1 = ((4 + quad) ^ (ln & 7)) * 8;
  int arow[4], brow[4];
  #pragma unroll
  for (int i = 0; i < 4; i++) arow[i] = (wm*64 + i*16 + ln) * 64;
  #pragma unroll
  for (int j = 0; j < 4; j++) brow[j] = (wn*64 + j*16 + ln) * 64;

  f32x4 acc[4][4] = {};
  STGA(0, 0); STGB(24576, 0); STGA(8192, 1);

  #pragma unroll
  for (int tt = 0; tt < 16; ++tt){
    const int a_cur = (tt % 3) * 8192;
    const int a_pf  = ((tt + 2) % 3) * 8192;
    const int b_cur = 24576 + (tt & 1) * 8192;
    const int b_pf  = 24576 + ((tt + 1) & 1) * 8192;

    if (tt < 15) { VM4(); } else { VM0(); }
    BARRAW(); SCHEDB();

    bf16x8 a01[2][2], bq[4][2];
    #pragma unroll
    for (int i = 0; i < 2; i++){
      a01[i][0] = *(const bf16x8*)&sm[a_cur + arow[i] + agr0];
      a01[i][1] = *(const bf16x8*)&sm[a_cur + arow[i] + agr1];
    }
    #pragma unroll
    for (int j = 0; j < 4; j++){
      bq[j][0] = *(const bf16x8*)&sm[b_cur + brow[j] + agr0];
      bq[j][1] = *(const bf16x8*)&sm[b_cur + brow[j] + agr1];
    }
    SCHEDB();
    if (tt < 15) STGB(b_pf, tt + 1);
    SCHEDB();
    WAIT_LGKM0(); SCHEDB();
    __builtin_amdgcn_s_setprio(1);
    #pragma unroll
    for (int i = 0; i < 2; i++)
      #pragma unroll
      for (int j = 0; j < 4; j++){
        MFMA_B16(acc[i][j], a01[i][0], bq[j][0]);
        MFMA_B16(acc[i][j], a01[i][1], bq[j][1]);
      }
    __builtin_amdgcn_s_setprio(0);

    bf16x8 a23[2][2];
    #pragma unroll
    for (int i = 0; i < 2; i++){
      a23[i][0] = *(const bf16x8*)&sm[a_cur + arow[2+i] + agr0];
      a23[i][1] = *(const bf16x8*)&sm[a_cur + arow[2+i] + agr1];
    }
    SCHEDB();
    if (tt < 14) STGA(a_pf, tt + 2);
    SCHEDB();
    WAIT_LGKM0(); SCHEDB();
    __builtin_amdgcn_s_setprio(1);
    #pragma unroll
    for (int i = 0; i < 2; i++)
      #pragma unroll
      for (int j = 0; j < 4; j++){
        MFMA_B16(acc[2+i][j], a23[i][0], bq[j][0]);
        MFMA_B16(acc[2+i][j], a23[i][1], bq[j][1]);
      }
    __builtin_amdgcn_s_setprio(0);
  }

  #pragma unroll
  for (int rb = 0; rb < 4; rb++)
    #pragma unroll
    for (int cb = 0; cb < 4; cb++)
      #pragma unroll
      for (int reg = 0; reg < 4; reg++){
        int row = m0 + wm*64 + rb*16 + quad*4 + reg;
        int col = n0 + wn*64 + cb*16 + ln;
        size_t off = (size_t)row*Dn + col;
        out[off] = acc[rb][cb][reg] + x[off];
      }
#undef STGA
#undef STGB
}

extern "C" void kernel_launch(void* const* d_in, const int* in_sizes, int n_in,
                              void* d_out, int out_size, void* d_ws, size_t ws_size,
                              hipStream_t stream){
  const float* x    = (const float*)d_in[0];
  const float* Wq   = (const float*)d_in[2];
  const float* Wk   = (const float*)d_in[3];
  const float* Wv   = (const float*)d_in[4];
  const float* Wout = (const float*)d_in[5];
  float* out = (float*)d_out;

  u16* ws = (u16*)d_ws;
  const size_t NW = (size_t)Dn * Dn;
  const size_t NX = (size_t)Bn * Sn * Dn;
  u16* wt  = ws;                // Wq^T(scaled),Wk^T,Wv^T,Wout^T
  u16* xb  = wt + 4*NW;         // x bf16
  u16* qb  = xb + NX;           // Q [b,h,s,d] (attn writes z in-place)
  u16* kb  = qb + NX;           // K [b,h,s,d]
  u16* vtb = kb + NX;           // Vt [b,h,d,s] (written directly by gemm_qkv)

  prep_kernel     <<<dim3(4096 + 1024), dim3(256), 0, stream>>>(x, Wq, Wk, Wv, Wout, xb, wt);
  gemm_qkv_kernel <<<dim3(1536), dim3(256), 0, stream>>>(xb, wt, qb, kb, vtb);
  attn_kernel     <<<dim3(8,16,4), dim3(256), 0, stream>>>(qb, kb, vtb, qb);
  gemm_out_kernel <<<dim3(512), dim3(256), 0, stream>>>(qb, wt + 3*NW, x, out);
}

// Round 3
// 252.857 us; speedup vs baseline: 1.1035x; 1.0091x over previous
//
#include <hip/hip_runtime.h>

#define Bn 4
#define Sn 2048
#define Dn 1024
#define Hn 16
#define DHn 64

typedef float f32x4 __attribute__((ext_vector_type(4)));
typedef short bf16x8 __attribute__((ext_vector_type(8)));
typedef unsigned short u16;
typedef unsigned int u32;
typedef unsigned short u16x8 __attribute__((ext_vector_type(8)));
typedef unsigned short u16x4 __attribute__((ext_vector_type(4)));
typedef u32 u32x4 __attribute__((ext_vector_type(4)));

union B8 { u32x4 u; bf16x8 s; u16x8 h; };

__device__ __forceinline__ u16 f2bf(float f){
  union { float f; u32 u; } v; v.f = f;
  return (u16)((v.u + 0x7fffu + ((v.u >> 16) & 1u)) >> 16);
}

// truncating pack: two fp32 -> {bf16(lo) | bf16(hi)<<16}. P>0 -> -0.2% uniform bias, negligible.
__device__ __forceinline__ u32 pack_bf2(float lo, float hi){
  union { float f; u32 u; } a, b;
  a.f = lo; b.f = hi;
  return __builtin_amdgcn_perm(b.u, a.u, 0x07060302u);
}

#if __has_builtin(__builtin_amdgcn_exp2f)
#define EXP2(x) __builtin_amdgcn_exp2f(x)
#define QSCALE 0.18033688011112042f   /* 0.125 * log2(e) */
#else
#define EXP2(x) __expf(x)
#define QSCALE 0.125f
#endif

#if __has_builtin(__builtin_amdgcn_global_load_lds)
#define G2L16(l, g) __builtin_amdgcn_global_load_lds((const __attribute__((address_space(1))) u32*)(g), \
                                                     (__attribute__((address_space(3))) u32*)(l), 16, 0, 0)
#else
#define G2L16(l, g) (*(bf16x8*)(l) = *(const bf16x8*)(g))
#endif

#define MFMA_B16(d, va, vb) (d) = __builtin_amdgcn_mfma_f32_16x16x32_bf16((va), (vb), (d), 0, 0, 0)
#define BARRAW() __builtin_amdgcn_s_barrier()
#define WAIT_LGKM0() asm volatile("s_waitcnt lgkmcnt(0)" ::: "memory")
#define VM4() asm volatile("s_waitcnt vmcnt(4)" ::: "memory")
#define VM0() asm volatile("s_waitcnt vmcnt(0)" ::: "memory")
#define SCHEDB() __builtin_amdgcn_sched_barrier(0)

// ---------------- merged prep: cast x (blocks 0..4095) + 4 weights (4096..5119) ----------------
__global__ void prep_kernel(const float* __restrict__ x,
                            const float* __restrict__ Wq, const float* __restrict__ Wk,
                            const float* __restrict__ Wv, const float* __restrict__ Wo,
                            u16* __restrict__ xb, u16* __restrict__ wt_all){
  __shared__ u16 tile[64*66];
  const int t = threadIdx.x;
  if (blockIdx.x < 4096){
    size_t i = ((size_t)blockIdx.x * 256 + t) * 8;
    float4 f0 = *(const float4*)(x + i);
    float4 f1 = *(const float4*)(x + i + 4);
    u16x8 o;
    o[0]=f2bf(f0.x); o[1]=f2bf(f0.y); o[2]=f2bf(f0.z); o[3]=f2bf(f0.w);
    o[4]=f2bf(f1.x); o[5]=f2bf(f1.y); o[6]=f2bf(f1.z); o[7]=f2bf(f1.w);
    *(u16x8*)(xb + i) = o;
    return;
  }
  const int wi = blockIdx.x - 4096;
  const int z = wi >> 8, r8 = wi & 255;
  const int k0 = (r8 >> 4) * 64, n0 = (r8 & 15) * 64;
  const float* w = (z == 0) ? Wq : (z == 1) ? Wk : (z == 2) ? Wv : Wo;
  const float scale = (z == 0) ? QSCALE : 1.0f;
  u16* wt = wt_all + (size_t)z * Dn * Dn;
  #pragma unroll
  for (int i = 0; i < 4; i++){
    int idx = i*256 + t;
    int r = idx >> 4, c4 = (idx & 15) * 4;
    float4 f = *(const float4*)(w + (size_t)(k0 + r)*Dn + n0 + c4);
    tile[r*66 + c4 + 0] = f2bf(f.x * scale);
    tile[r*66 + c4 + 1] = f2bf(f.y * scale);
    tile[r*66 + c4 + 2] = f2bf(f.z * scale);
    tile[r*66 + c4 + 3] = f2bf(f.w * scale);
  }
  __syncthreads();
  #pragma unroll
  for (int i = 0; i < 4; i++){
    int idx = i*256 + t;
    int nr = idx >> 4, kc4 = (idx & 15) * 4;
    u16x4 o;
    o[0] = tile[(kc4+0)*66 + nr];
    o[1] = tile[(kc4+1)*66 + nr];
    o[2] = tile[(kc4+2)*66 + nr];
    o[3] = tile[(kc4+3)*66 + nr];
    *(u16x4*)(wt + (size_t)(n0 + nr)*Dn + k0 + kc4) = o;
  }
}

// ---------------- QKV GEMM: 128^2 tile, BK=64, A-tri/B-dbuf, 1 barrier/K-tile ----------------
__launch_bounds__(256)
__global__ void gemm_qkv_kernel(const u16* __restrict__ xb, const u16* __restrict__ wt_all,
                                u16* __restrict__ qb, u16* __restrict__ kb, u16* __restrict__ vtb){
  __shared__ u16 sm[40960];   // 80 KB
  const int t = threadIdx.x;
  const int lane = t & 63, wave = t >> 6;
  const int ln = lane & 15, quad = lane >> 4;
  const int wm = wave >> 1, wn = wave & 1;

  // T1: XCD-chunked bijective swizzle (1536 = 8*192), m-outer n-inner within chunk
  const int lin = blockIdx.x;
  const int wg = (lin & 7) * 192 + (lin >> 3);
  const int zsel = wg >> 9;
  const int rem = wg & 511;
  const int m0 = (rem >> 3) * 128;
  const int n0 = (rem & 7) * 128;
  const u16* wt = wt_all + (size_t)zsel * Dn * Dn;

  const u16* ap[4]; const u16* bp[4]; int ldo[4];
  #pragma unroll
  for (int p = 0; p < 4; p++){
    int idx = p*256 + t;
    int r = idx >> 3, g = (idx & 7) ^ (r & 7);
    ap[p] = xb + (size_t)(m0 + r)*Dn + g*8;
    bp[p] = wt + (size_t)(n0 + r)*Dn + g*8;
    ldo[p] = idx * 8;
  }
#define STGA(buf, tt) do { _Pragma("unroll") for (int p = 0; p < 4; p++) \
    G2L16(&sm[(buf) + ldo[p]], ap[p] + (size_t)(tt)*64); } while(0)
#define STGB(buf, tt) do { _Pragma("unroll") for (int p = 0; p < 4; p++) \
    G2L16(&sm[(buf) + ldo[p]], bp[p] + (size_t)(tt)*64); } while(0)

  const int agr0 = ((    quad) ^ (ln & 7)) * 8;
  const int agr1 = ((4 + quad) ^ (ln & 7)) * 8;
  int arow[4], brow[4];
  #pragma unroll
  for (int i = 0; i < 4; i++) arow[i] = (wm*64 + i*16 + ln) * 64;
  #pragma unroll
  for (int j = 0; j < 4; j++) brow[j] = (wn*64 + j*16 + ln) * 64;

  f32x4 acc[4][4] = {};

  STGA(0, 0); STGB(24576, 0); STGA(8192, 1);

  #pragma unroll
  for (int tt = 0; tt < 16; ++tt){
    const int a_cur = (tt % 3) * 8192;
    const int a_pf  = ((tt + 2) % 3) * 8192;
    const int b_cur = 24576 + (tt & 1) * 8192;
    const int b_pf  = 24576 + ((tt + 1) & 1) * 8192;

    if (tt < 15) { VM4(); } else { VM0(); }
    BARRAW(); SCHEDB();

    bf16x8 a01[2][2], bq[4][2];
    #pragma unroll
    for (int i = 0; i < 2; i++){
      a01[i][0] = *(const bf16x8*)&sm[a_cur + arow[i] + agr0];
      a01[i][1] = *(const bf16x8*)&sm[a_cur + arow[i] + agr1];
    }
    #pragma unroll
    for (int j = 0; j < 4; j++){
      bq[j][0] = *(const bf16x8*)&sm[b_cur + brow[j] + agr0];
      bq[j][1] = *(const bf16x8*)&sm[b_cur + brow[j] + agr1];
    }
    SCHEDB();
    if (tt < 15) STGB(b_pf, tt + 1);
    SCHEDB();
    WAIT_LGKM0(); SCHEDB();
    __builtin_amdgcn_s_setprio(1);
    #pragma unroll
    for (int i = 0; i < 2; i++)
      #pragma unroll
      for (int j = 0; j < 4; j++){
        MFMA_B16(acc[i][j], a01[i][0], bq[j][0]);
        MFMA_B16(acc[i][j], a01[i][1], bq[j][1]);
      }
    __builtin_amdgcn_s_setprio(0);

    bf16x8 a23[2][2];
    #pragma unroll
    for (int i = 0; i < 2; i++){
      a23[i][0] = *(const bf16x8*)&sm[a_cur + arow[2+i] + agr0];
      a23[i][1] = *(const bf16x8*)&sm[a_cur + arow[2+i] + agr1];
    }
    SCHEDB();
    if (tt < 14) STGA(a_pf, tt + 2);
    SCHEDB();
    WAIT_LGKM0(); SCHEDB();
    __builtin_amdgcn_s_setprio(1);
    #pragma unroll
    for (int i = 0; i < 2; i++)
      #pragma unroll
      for (int j = 0; j < 4; j++){
        MFMA_B16(acc[2+i][j], a23[i][0], bq[j][0]);
        MFMA_B16(acc[2+i][j], a23[i][1], bq[j][1]);
      }
    __builtin_amdgcn_s_setprio(0);
  }

  __syncthreads();
  u16* Cs = sm;
  if (zsel < 2){
    u16* outp = (zsel == 0) ? qb : kb;
    #pragma unroll
    for (int rb = 0; rb < 4; rb++)
      #pragma unroll
      for (int cb = 0; cb < 4; cb++)
        #pragma unroll
        for (int reg = 0; reg < 4; reg++)
          Cs[(wm*64 + rb*16 + quad*4 + reg)*136 + wn*64 + cb*16 + ln] = f2bf(acc[rb][cb][reg]);
    __syncthreads();
    #pragma unroll
    for (int i = 0; i < 8; i++){
      int idx = i*256 + t;
      int r = idx >> 4, c8 = (idx & 15) * 8;
      bf16x8 vdat = *(const bf16x8*)&Cs[r*136 + c8];
      int row = m0 + r, bb = row >> 11, s = row & 2047;
      int col = n0 + c8, hh = col >> 6, d = col & 63;
      *(bf16x8*)(outp + (((size_t)bb*Hn + hh)*Sn + s)*DHn + d) = vdat;
    }
  } else {
    #pragma unroll
    for (int rb = 0; rb < 4; rb++)
      #pragma unroll
      for (int cb = 0; cb < 4; cb++){
        u16x4 o;
        #pragma unroll
        for (int reg = 0; reg < 4; reg++) o[reg] = f2bf(acc[rb][cb][reg]);
        *(u16x4*)&Cs[(wn*64 + cb*16 + ln)*136 + wm*64 + rb*16 + quad*4] = o;
      }
    __syncthreads();
    #pragma unroll
    for (int i = 0; i < 8; i++){
      int idx = i*256 + t;
      int c = idx >> 4, r8 = (idx & 15) * 8;
      bf16x8 vdat = *(const bf16x8*)&Cs[c*136 + r8];
      int col = n0 + c, hh = col >> 6, d = col & 63;
      int row = m0 + r8, bb = row >> 11, s = row & 2047;
      *(bf16x8*)(vtb + (((size_t)bb*Hn + hh)*DHn + d)*Sn + s) = vdat;
    }
  }
#undef STGA
#undef STGB
}

// ---------------- attention: S^T formulation, 8 waves x 32 q-rows, XOR-swizzled LDS ----------------
// 512 thr/block, grid 512, 2 blocks/CU -> 16 waves/CU (4/SIMD): 2x wave-level
// parallelism vs the 4-wave version to hide the per-iter serial chain
// (K-read -> QK^T -> exp/pack -> V-read -> PV). K/V LDS: pitch 64, granule
// XOR swizzle (g^(row&7)) - reads are 2-way max per quarter-wave (free, m136).
__launch_bounds__(512, 4)
__global__ void attn_kernel(const u16* q, const u16* __restrict__ k,
                            const u16* __restrict__ vt, u16* z){
  __shared__ u16 Ks[2][64*64];   // [key][d], swizzled granules
  __shared__ u16 Vs[2][64*64];   // [d][key'] column-shuffled + swizzled granules
  const int t = threadIdx.x;
  const int wave = t >> 6, lane = t & 63;
  const int ln = lane & 15, quad = lane >> 4;
  const int lin = blockIdx.x + 8*(blockIdx.y + 16*blockIdx.z);
  const int wgs = (lin & 7)*64 + (lin >> 3);
  const int qt = wgs & 7, h = (wgs >> 3) & 15, b = wgs >> 7;
  const size_t bh = (size_t)b * Hn + h;
  const int q0 = qt*256 + wave*32;
  const u16* qp = q + bh * Sn * DHn;
  const u16* kp = k + bh * Sn * DHn;
  const u16* vp = vt + bh * DHn * Sn;

  bf16x8 qf[2][2];
  #pragma unroll
  for (int n = 0; n < 2; n++)
    #pragma unroll
    for (int kq = 0; kq < 2; kq++)
      qf[n][kq] = *(const bf16x8*)(qp + (size_t)(q0 + n*16 + ln)*DHn + kq*32 + quad*8);

  f32x4 zacc[4][2] = {};
  float dacc[2] = {0.f, 0.f};

  // staging: thread t stages granule a of row r for K and (shuffled) V
  const int r = t >> 3, a = t & 7;
  const int ksg = a >> 2, q1 = ((a&3)*2)&3, h1 = (a&3) >> 1;
  const int vc1 = ksg*32 + q1*8 + h1*4;
  const int vc2 = ksg*32 + (((q1+1)&3))*8 + h1*4;
  const int kpos  = r*64 + (a ^ (r&7))*8;
  const int vpos1 = r*64 + ((vc1>>3) ^ (r&7))*8 + (vc1 & 7);
  const int vpos2 = r*64 + ((vc2>>3) ^ (r&7))*8 + (vc2 & 7);

  bf16x8 rk, rv;
  rk = *(const bf16x8*)(kp + (size_t)r*DHn + a*8);
  rv = *(const bf16x8*)(vp + (size_t)r*Sn + a*8);
  {
    *(bf16x8*)&Ks[0][kpos] = rk;
    u16x4 lo = *(u16x4*)&rv;
    u16x4 hi = *((u16x4*)&rv + 1);
    *(u16x4*)&Vs[0][vpos1] = lo;
    *(u16x4*)&Vs[0][vpos2] = hi;
  }

  // swizzled read column offsets
  const int kg0 = ((    quad) ^ (ln & 7)) * 8;   // kq=0 / ks=0 granule
  const int kg1 = ((4 + quad) ^ (ln & 7)) * 8;   // kq=1 / ks=1 granule

  for (int kt = 0; kt < Sn/64; kt++){
    const int cur = kt & 1;
    __syncthreads();

    if (kt + 1 < Sn/64){
      rk = *(const bf16x8*)(kp + (size_t)((kt+1)*64 + r)*DHn + a*8);
      rv = *(const bf16x8*)(vp + (size_t)r*Sn + (kt+1)*64 + a*8);
    }
    const u16* Kc = Ks[cur];
    const u16* Vc = Vs[cur];

    #pragma unroll
    for (int ks = 0; ks < 2; ks++){
      f32x4 sacc[2][2] = {};
      #pragma unroll
      for (int kq = 0; kq < 2; kq++){
        const int kgo = kq ? kg1 : kg0;
        bf16x8 ka[2];
        #pragma unroll
        for (int m2 = 0; m2 < 2; m2++)
          ka[m2] = *(const bf16x8*)&Kc[((2*ks + m2)*16 + ln)*64 + kgo];
        #pragma unroll
        for (int m2 = 0; m2 < 2; m2++)
          #pragma unroll
          for (int n = 0; n < 2; n++)
            sacc[m2][n] = __builtin_amdgcn_mfma_f32_16x16x32_bf16(ka[m2], qf[n][kq], sacc[m2][n], 0, 0, 0);
      }
      B8 pb[2];
      #pragma unroll
      for (int n = 0; n < 2; n++){
        f32x4 s0 = sacc[0][n], s1 = sacc[1][n];
        float a0 = EXP2(s0[0]), a1 = EXP2(s0[1]), a2 = EXP2(s0[2]), a3 = EXP2(s0[3]);
        float b0 = EXP2(s1[0]), b1 = EXP2(s1[1]), b2 = EXP2(s1[2]), b3 = EXP2(s1[3]);
        dacc[n] += ((a0 + a1) + (a2 + a3)) + ((b0 + b1) + (b2 + b3));
        pb[n].u = (u32x4){pack_bf2(a0, a1), pack_bf2(a2, a3), pack_bf2(b0, b1), pack_bf2(b2, b3)};
      }
      const int vgo = ks ? kg1 : kg0;
      #pragma unroll
      for (int mtd = 0; mtd < 4; mtd++){
        bf16x8 va = *(const bf16x8*)&Vc[(mtd*16 + ln)*64 + vgo];
        #pragma unroll
        for (int n = 0; n < 2; n++)
          zacc[mtd][n] = __builtin_amdgcn_mfma_f32_16x16x32_bf16(va, pb[n].s, zacc[mtd][n], 0, 0, 0);
      }
    }

    if (kt + 1 < Sn/64){
      const int nxt = (kt+1) & 1;
      *(bf16x8*)&Ks[nxt][kpos] = rk;
      u16x4 lo = *(u16x4*)&rv;
      u16x4 hi = *((u16x4*)&rv + 1);
      *(u16x4*)&Vs[nxt][vpos1] = lo;
      *(u16x4*)&Vs[nxt][vpos2] = hi;
    }
  }

  float inv[2];
  #pragma unroll
  for (int n = 0; n < 2; n++){
    float d = dacc[n];
    d += __shfl_xor(d, 16, 64);
    d += __shfl_xor(d, 32, 64);
    inv[n] = 1.0f / d;
  }

  #pragma unroll
  for (int mtd = 0; mtd < 4; mtd++)
    #pragma unroll
    for (int n = 0; n < 2; n++){
      u16x4 o;
      #pragma unroll
      for (int j = 0; j < 4; j++) o[j] = f2bf(zacc[mtd][n][j] * inv[n]);
      *(u16x4*)(z + (bh*Sn + (size_t)(q0 + n*16 + ln))*DHn + mtd*16 + quad*4) = o;
    }
}

// ---------------- out = z * Wout^T + x: same A-tri/B-dbuf template, K-chunk 64 == head ----------------
__launch_bounds__(256)
__global__ void gemm_out_kernel(const u16* __restrict__ zb, const u16* __restrict__ wt,
                                const float* __restrict__ x, float* __restrict__ out){
  __shared__ u16 sm[40960];   // 80 KB
  const int t = threadIdx.x;
  const int lane = t & 63, wave = t >> 6;
  const int ln = lane & 15, quad = lane >> 4;
  const int wm = wave >> 1, wn = wave & 1;

  const int lin = blockIdx.x;
  const int wg = (lin & 7) * 64 + (lin >> 3);
  const int m0 = (wg >> 3) * 128;
  const int n0 = (wg & 7) * 128;

  const u16* ap[4]; const u16* bp[4]; int ldo[4];
  #pragma unroll
  for (int p = 0; p < 4; p++){
    int idx = p*256 + t;
    int r = idx >> 3, g = (idx & 7) ^ (r & 7);
    int row = m0 + r, bb = row >> 11, s = row & 2047;
    ap[p] = zb + ((size_t)bb*Hn*Sn + s)*DHn + g*8;    // head-0 base; head stride Sn*DHn
    bp[p] = wt + (size_t)(n0 + r)*Dn + g*8;
    ldo[p] = idx * 8;
  }
#define STGA(buf, tt) do { _Pragma("unroll") for (int p = 0; p < 4; p++) \
    G2L16(&sm[(buf) + ldo[p]], ap[p] + (size_t)(tt)*Sn*DHn); } while(0)
#define STGB(buf, tt) do { _Pragma("unroll") for (int p = 0; p < 4; p++) \
    G2L16(&sm[(buf) + ldo[p]], bp[p] + (size_t)(tt)*64); } while(0)

  const int agr0 = ((    quad) ^ (ln & 7)) * 8;
  const int agr1 = ((4 + quad) ^ (ln & 7)) * 8;
  int arow[4], brow[4];
  #pragma unroll
  for (int i = 0; i < 4; i++) arow[i] = (wm*64 + i*16 + ln) * 64;
  #pragma unroll
  for (int j = 0; j < 4; j++) brow[j] = (wn*64 + j*16 + ln) * 64;

  f32x4 acc[4][4] = {};
  STGA(0, 0); STGB(24576, 0); STGA(8192, 1);

  #pragma unroll
  for (int tt = 0; tt < 16; ++tt){
    const int a_cur = (tt % 3) * 8192;
    const int a_pf  = ((tt + 2) % 3) * 8192;
    const int b_cur = 24576 + (tt & 1) * 8192;
    const int b_pf  = 24576 + ((tt + 1) & 1) * 8192;

    if (tt < 15) { VM4(); } else { VM0(); }
    BARRAW(); SCHEDB();

    bf16x8 a01[2][2], bq[4][2];
    #pragma unroll
    for (int i = 0; i < 2; i++){
      a01[i][0] = *(const bf16x8*)&sm[a_cur + arow[i] + agr0];
      a01[i][1] = *(const bf16x8*)&sm[a_cur + arow[i] + agr1];
    }
    #pragma unroll
    for (int j = 0; j < 4; j++){
      bq[j][0] = *(const bf16x8*)&sm[b_cur + brow[j] + agr0];
      bq[j][1] = *(const bf16x8*)&sm[b_cur + brow[j] + agr1];
    }
    SCHEDB();
    if (tt < 15) STGB(b_pf, tt + 1);
    SCHEDB();
    WAIT_LGKM0(); SCHEDB();
    __builtin_amdgcn_s_setprio(1);
    #pragma unroll
    for (int i = 0; i < 2; i++)
      #pragma unroll
      for (int j = 0; j < 4; j++){
        MFMA_B16(acc[i][j], a01[i][0], bq[j][0]);
        MFMA_B16(acc[i][j], a01[i][1], bq[j][1]);
      }
    __builtin_amdgcn_s_setprio(0);

    bf16x8 a23[2][2];
    #pragma unroll
    for (int i = 0; i < 2; i++){
      a23[i][0] = *(const bf16x8*)&sm[a_cur + arow[2+i] + agr0];
      a23[i][1] = *(const bf16x8*)&sm[a_cur + arow[2+i] + agr1];
    }
    SCHEDB();
    if (tt < 14) STGA(a_pf, tt + 2);
    SCHEDB();
    WAIT_LGKM0(); SCHEDB();
    __builtin_amdgcn_s_setprio(1);
    #pragma unroll
    for (int i = 0; i < 2; i++)
      #pragma unroll
      for (int j = 0; j < 4; j++){
        MFMA_B16(acc[2+i][j], a23[i][0], bq[j][0]);
        MFMA_B16(acc[2+i][j], a23[i][1], bq[j][1]);
      }
    __builtin_amdgcn_s_setprio(0);
  }

  #pragma unroll
  for (int rb = 0; rb < 4; rb++)
    #pragma unroll
    for (int cb = 0; cb < 4; cb++)
      #pragma unroll
      for (int reg = 0; reg < 4; reg++){
        int row = m0 + wm*64 + rb*16 + quad*4 + reg;
        int col = n0 + wn*64 + cb*16 + ln;
        size_t off = (size_t)row*Dn + col;
        out[off] = acc[rb][cb][reg] + x[off];
      }
#undef STGA
#undef STGB
}

extern "C" void kernel_launch(void* const* d_in, const int* in_sizes, int n_in,
                              void* d_out, int out_size, void* d_ws, size_t ws_size,
                              hipStream_t stream){
  const float* x    = (const float*)d_in[0];
  const float* Wq   = (const float*)d_in[2];
  const float* Wk   = (const float*)d_in[3];
  const float* Wv   = (const float*)d_in[4];
  const float* Wout = (const float*)d_in[5];
  float* out = (float*)d_out;

  u16* ws = (u16*)d_ws;
  const size_t NW = (size_t)Dn * Dn;
  const size_t NX = (size_t)Bn * Sn * Dn;
  u16* wt  = ws;                // Wq^T(scaled),Wk^T,Wv^T,Wout^T
  u16* xb  = wt + 4*NW;         // x bf16
  u16* qb  = xb + NX;           // Q [b,h,s,d] (attn writes z in-place)
  u16* kb  = qb + NX;           // K [b,h,s,d]
  u16* vtb = kb + NX;           // Vt [b,h,d,s] (written directly by gemm_qkv)

  prep_kernel     <<<dim3(4096 + 1024), dim3(256), 0, stream>>>(x, Wq, Wk, Wv, Wout, xb, wt);
  gemm_qkv_kernel <<<dim3(1536), dim3(256), 0, stream>>>(xb, wt, qb, kb, vtb);
  attn_kernel     <<<dim3(8,16,4), dim3(512), 0, stream>>>(qb, kb, vtb, qb);
  gemm_out_kernel <<<dim3(512), dim3(256), 0, stream>>>(qb, wt + 3*NW, x, out);
}